// Round 1
// baseline (179.358 us; speedup 1.0000x reference)
//
#include <hip/hip_runtime.h>
#include <hip/hip_fp16.h>

#define NNODES 4096
#define NEDGES 500000
#define NPAIRS 2000000
#define EDIM   16
#define LMAX   5

typedef int v4i __attribute__((ext_vector_type(4)));

__device__ __forceinline__ v4i ntload4(const int* p) {
  return __builtin_nontemporal_load((const v4i*)p);
}

// ---------------------------------------------------------------------------
// Kernel 0: dots[l*NEDGES + e] = fp16(dot(edge_attr[e,:], edge_weights[l,:]))
// 2 edges/thread -> half2 stores (4B/lane, 256B/wave per slab).
// fp16 halves the downstream gather footprint (5MB total, ~L2-resident/XCD).
// ---------------------------------------------------------------------------
__global__ __launch_bounds__(256) void dots_kernel(
    const float* __restrict__ edge_attr,
    const float* __restrict__ ew,
    __half* __restrict__ dots) {
  __shared__ float w[LMAX * EDIM];
  int tid = threadIdx.x;
  if (tid < LMAX * EDIM) w[tid] = ew[tid];
  __syncthreads();

  int e0 = (blockIdx.x * 256 + tid) * 2;  // NEDGES even -> e0+1 always valid
  if (e0 >= NEDGES) return;

  const float4* ra = (const float4*)(edge_attr + (size_t)e0 * EDIM);
  float4 a0 = ra[0], a1 = ra[1], a2 = ra[2], a3 = ra[3];
  float4 b0 = ra[4], b1 = ra[5], b2 = ra[6], b3 = ra[7];  // edge e0+1
  float va[16] = {a0.x, a0.y, a0.z, a0.w, a1.x, a1.y, a1.z, a1.w,
                  a2.x, a2.y, a2.z, a2.w, a3.x, a3.y, a3.z, a3.w};
  float vb[16] = {b0.x, b0.y, b0.z, b0.w, b1.x, b1.y, b1.z, b1.w,
                  b2.x, b2.y, b2.z, b2.w, b3.x, b3.y, b3.z, b3.w};
#pragma unroll
  for (int l = 0; l < LMAX; ++l) {
    float da = 0.f, db = 0.f;
#pragma unroll
    for (int k = 0; k < EDIM; ++k) {
      da += va[k] * w[l * EDIM + k];
      db += vb[k] * w[l * EDIM + k];
    }
    __half2 h;
    h.x = __float2half(da);
    h.y = __float2half(db);
    *(__half2*)(dots + (size_t)l * NEDGES + e0) = h;  // e0 even -> 4B aligned
  }
}

// ---------------------------------------------------------------------------
// Fused mean + transpose.
// Per-pair mean computed in-register inside the transpose tile load phase:
// kills the 8MB mean intermediate (8MB write + 8MB read) and one dispatch,
// gives each thread 4 pairs x up-to-5 = 20 independent gathers in flight per
// unrolled chunk (vs <=5 in the old mean_kernel -> latency-bound at 29% HBM),
// and overlaps the 56MB zero-region writes with gather latency.
// ---------------------------------------------------------------------------
__device__ __forceinline__ float pair_mean(
    const __half* __restrict__ dots, int len,
    int i0, int i1, int i2, int i3, int i4) {
  len = min(max(len, 0), LMAX);
  // Independent predicated loads: all issue before the dependent sum.
  float v0 = (len > 0) ? __half2float(dots[i0]) : 0.f;
  float v1 = (len > 1) ? __half2float(dots[1 * NEDGES + i1]) : 0.f;
  float v2 = (len > 2) ? __half2float(dots[2 * NEDGES + i2]) : 0.f;
  float v3 = (len > 3) ? __half2float(dots[3 * NEDGES + i3]) : 0.f;
  float v4 = (len > 4) ? __half2float(dots[4 * NEDGES + i4]) : 0.f;
  float s = ((v0 + v1) + (v2 + v3)) + v4;
  return (len > 0) ? s / (float)len : 0.f;
}

// Grid: x = src tile (uniform work), y = dst tile. Gather-heavy tiles are
// y in [0,8) -> the FIRST 512 blocks dispatched (long tasks first, spread
// round-robin over all 8 XCDs); pure-zero tiles backfill behind them.
__global__ __launch_bounds__(256) void fused_mean_transpose(
    const int* __restrict__ path_idx,
    const int* __restrict__ path_lens,
    const __half* __restrict__ dots,
    float* __restrict__ out) {
  const int src0 = blockIdx.x * 64;
  const int dst0 = blockIdx.y * 64;
  const int tid = threadIdx.x;  // 0..255

  if (dst0 * NNODES >= NPAIRS) {  // whole tile past valid region -> zeros
    float4 z = {0.f, 0.f, 0.f, 0.f};
#pragma unroll
    for (int i = 0; i < 4; ++i) {
      int slot = tid + i * 256;  // 0..1023
      int a = slot >> 4;         // src row 0..63
      int c = slot & 15;         // float4 col
      ((float4*)(out + (size_t)(src0 + a) * NNODES + dst0))[c] = z;
    }
    return;
  }

  __shared__ float tile[64][65];

#pragma unroll
  for (int i = 0; i < 4; ++i) {
    int slot = tid + i * 256;
    int a = slot >> 4;  // dst offset within tile
    int c = slot & 15;  // float4 group along src
    int p = (dst0 + a) * NNODES + src0 + 4 * c;  // multiple of 4
    float4 v = {0.f, 0.f, 0.f, 0.f};
    if (p < NPAIRS) {  // NPAIRS % 4 == 0 -> all 4 pairs valid together
      // p multiple of 4 -> p*5 ints = 16B aligned; 20 ints = 5 dwordx4 NT.
      v4i ln = ntload4(path_lens + p);
      const int* q = path_idx + (size_t)p * LMAX;
      v4i A = ntload4(q);
      v4i B = ntload4(q + 4);
      v4i C = ntload4(q + 8);
      v4i D = ntload4(q + 12);
      v4i E = ntload4(q + 16);
      v.x = pair_mean(dots, ln[0], A[0], A[1], A[2], A[3], B[0]);
      v.y = pair_mean(dots, ln[1], B[1], B[2], B[3], C[0], C[1]);
      v.z = pair_mean(dots, ln[2], C[2], C[3], D[0], D[1], D[2]);
      v.w = pair_mean(dots, ln[3], D[3], E[0], E[1], E[2], E[3]);
    }
    tile[a][4 * c + 0] = v.x;
    tile[a][4 * c + 1] = v.y;
    tile[a][4 * c + 2] = v.z;
    tile[a][4 * c + 3] = v.w;
  }
  __syncthreads();
#pragma unroll
  for (int i = 0; i < 4; ++i) {
    int slot = tid + i * 256;
    int a = slot >> 4;  // src offset
    int c = slot & 15;
    float4 v;
    v.x = tile[4 * c + 0][a];
    v.y = tile[4 * c + 1][a];
    v.z = tile[4 * c + 2][a];
    v.w = tile[4 * c + 3][a];
    ((float4*)(out + (size_t)(src0 + a) * NNODES + dst0))[c] = v;
  }
}

// ---------------------------------------------------------------------------
// Fallback (ws too small): memset + direct fp32 scatter.
// ---------------------------------------------------------------------------
__global__ __launch_bounds__(256) void scatter_kernel(
    const float* __restrict__ edge_attr,
    const float* __restrict__ ew,
    const int* __restrict__ path_idx,
    const int* __restrict__ path_lens,
    float* __restrict__ out) {
  __shared__ float w[LMAX * EDIM];
  if (threadIdx.x < LMAX * EDIM) w[threadIdx.x] = ew[threadIdx.x];
  __syncthreads();

  int p = blockIdx.x * 256 + threadIdx.x;
  if (p >= NPAIRS) return;

  int len = path_lens[p];
  len = min(max(len, 0), LMAX);

  const int* row = path_idx + (size_t)p * LMAX;
  float s = 0.f;
  for (int l = 0; l < len; ++l) {
    int idx = row[l];
    const float4* r = (const float4*)(edge_attr + (size_t)idx * EDIM);
    float4 a0 = r[0], a1 = r[1], a2 = r[2], a3 = r[3];
    const float* wl = &w[l * EDIM];
    s += a0.x * wl[0] + a0.y * wl[1] + a0.z * wl[2] + a0.w * wl[3] +
         a1.x * wl[4] + a1.y * wl[5] + a1.z * wl[6] + a1.w * wl[7] +
         a2.x * wl[8] + a2.y * wl[9] + a2.z * wl[10] + a2.w * wl[11] +
         a3.x * wl[12] + a3.y * wl[13] + a3.z * wl[14] + a3.w * wl[15];
  }
  float m = (len > 0) ? (s / (float)len) : 0.f;
  int src = p & (NNODES - 1);
  int dst = p >> 12;
  out[(size_t)src * NNODES + dst] = m;
}

extern "C" void kernel_launch(void* const* d_in, const int* in_sizes, int n_in,
                              void* d_out, int out_size, void* d_ws, size_t ws_size,
                              hipStream_t stream) {
  // setup_inputs order: x, edge_attr, edge_weights, path_idx, path_lens, pair_id
  const float* edge_attr = (const float*)d_in[1];
  const float* edge_w    = (const float*)d_in[2];
  const int*   path_idx  = (const int*)d_in[3];
  const int*   path_lens = (const int*)d_in[4];
  float* out = (float*)d_out;

  // ws layout: dots fp16 only (5MB) -- mean intermediate eliminated by fusion.
  const size_t need = (size_t)LMAX * NEDGES * sizeof(__half);

  if (ws_size >= need) {
    __half* dots = (__half*)d_ws;

    dots_kernel<<<(NEDGES / 2 + 255) / 256, 256, 0, stream>>>(edge_attr, edge_w, dots);
    dim3 grid(64, 64), block(256, 1);  // x = src tile, y = dst tile
    fused_mean_transpose<<<grid, block, 0, stream>>>(path_idx, path_lens, dots, out);
  } else {
    hipMemsetAsync(d_out, 0, (size_t)out_size * sizeof(float), stream);
    scatter_kernel<<<(NPAIRS + 255) / 256, 256, 0, stream>>>(
        edge_attr, edge_w, path_idx, path_lens, out);
  }
}